// Round 6
// baseline (495.822 us; speedup 1.0000x reference)
//
#include <hip/hip_runtime.h>
#include <hip/hip_bf16.h>

#define NB 64     // batch
#define NI 2048   // input capsules
#define ND 16     // d_in
#define NJ 32     // output capsules
#define NE 32     // d_out
#define NIP (NI/2)  // i-pairs
#define NKC 64    // split-K chunks in wsum

typedef __attribute__((ext_vector_type(8))) short bfrag;   // 8 bf16 (4 VGPRs)
typedef __attribute__((ext_vector_type(4))) float f32x4;

// two floats -> packed bf16x2 (v_cvt_pk_bf16_f32 on gfx950), RNE
__device__ inline unsigned pk2bf(float a, float b) {
    __hip_bfloat162 h = __float22bfloat162_rn(make_float2(a, b));
    return *reinterpret_cast<unsigned*>(&h);
}

// add value rotated by N within each 16-lane DPP row (row_ror:N)
template <int N>
__device__ inline float rot16_add(float v) {
    int r = __builtin_amdgcn_mov_dpp(__float_as_int(v), 0x120 + N, 0xf, 0xf, false);
    return v + __int_as_float(r);
}

// ---------------------------------------------------------------------------
// lgsm_k: fused logits + softmax. Block = 16 b x 16 i x ALL 32 j (8 waves,
// 4 j each). Logits via K=16-padded mfma + DPP e-reduction into 32KB LDS,
// one barrier, softmax over j, write c[j][i][b] to global.
// x converted to bf16 inline (active quads only). grid (4 bb, 128 ic).
// ---------------------------------------------------------------------------
__global__ __launch_bounds__(512) void lgsm_k(
    const float* __restrict__ x,      // [NB][NI][ND] fp32
    const short* __restrict__ Wb,     // [NJ][NIP][NE][32] bf16
    const float* __restrict__ Oacc,   // [NB][NJ][NE]
    float* __restrict__ c)            // [NJ][NI][NB]
{
    const int b0   = blockIdx.x * 16;
    const int i0   = blockIdx.y * 16;
    const int t    = threadIdx.x;
    const int wv   = t >> 6;           // 0..7 -> j-set wv*4..wv*4+3
    const int ln   = t & 63;
    const int m    = ln & 15;
    const int quad = ln >> 4;

    __shared__ float lp[NJ][16][16];   // [j][i][b] 32 KB

    // Hoist Oacc fragments for this wave's 4 j's.
    float O0[4][4], O1[4][4];
#pragma unroll
    for (int jj = 0; jj < 4; ++jj) {
        const int j = wv * 4 + jj;
#pragma unroll
        for (int r = 0; r < 4; ++r) {
            const int b = b0 + quad * 4 + r;
            O0[jj][r] = Oacc[((size_t)b * NJ + j) * NE + m];
            O1[jj][r] = Oacc[((size_t)b * NJ + j) * NE + 16 + m];
        }
    }

    const int  bA  = b0 + m;        // A-operand row (b) this lane supplies
    const bool act = quad < 2;      // quads 0,1 carry k=0..15 (d); 2,3 zero pad
    const int  d0  = quad * 8;

    for (int il = 0; il < 16; ++il) {
        const int i = i0 + il;
        const int ip = i >> 1, isel = i & 1;
        bfrag av = (bfrag)0;
        if (act) {
            const float4* xp = reinterpret_cast<const float4*>(
                x + ((size_t)bA * NI + i) * ND + d0);
            float4 x0 = xp[0], x1 = xp[1];
            unsigned* avu = reinterpret_cast<unsigned*>(&av);
            avu[0] = pk2bf(x0.x, x0.y);
            avu[1] = pk2bf(x0.z, x0.w);
            avu[2] = pk2bf(x1.x, x1.y);
            avu[3] = pk2bf(x1.z, x1.w);
        }
#pragma unroll
        for (int jj = 0; jj < 4; ++jj) {
            const int j = wv * 4 + jj;
            bfrag bv0 = (bfrag)0, bv1 = (bfrag)0;
            if (act) {
                const short* wp = Wb + (((size_t)j * NIP + ip) * NE + m) * 32
                                     + isel * 16 + d0;
                bv0 = *reinterpret_cast<const bfrag*>(wp);
                bv1 = *reinterpret_cast<const bfrag*>(wp + 16 * 32);
            }
            f32x4 z = {0.f, 0.f, 0.f, 0.f};
            f32x4 U0 = __builtin_amdgcn_mfma_f32_16x16x32_bf16(av, bv0, z, 0, 0, 0);
            f32x4 U1 = __builtin_amdgcn_mfma_f32_16x16x32_bf16(av, bv1, z, 0, 0, 0);

            float v4[4];
#pragma unroll
            for (int r = 0; r < 4; ++r) {
                float v = fmaf(U0[r], O0[jj][r], U1[r] * O1[jj][r]);
                v = rot16_add<1>(v);
                v = rot16_add<2>(v);
                v = rot16_add<4>(v);
                v = rot16_add<8>(v);
                v4[r] = v;
            }
            if (m == 0) {
                *reinterpret_cast<float4*>(&lp[j][il][quad * 4]) =
                    make_float4(v4[0], v4[1], v4[2], v4[3]);
            }
        }
    }
    __syncthreads();

    // softmax over j: threads 0..255 each own one (i,b) row.
    if (t < 256) {
        const int i = t >> 4, b = t & 15;
        float v[NJ];
        float mx = -1e30f;
#pragma unroll
        for (int jx = 0; jx < NJ; ++jx) {
            v[jx] = lp[jx][i][b];
            mx = fmaxf(mx, v[jx]);
        }
        float sum = 0.f;
#pragma unroll
        for (int jx = 0; jx < NJ; ++jx) {
            v[jx] = __expf(v[jx] - mx);
            sum += v[jx];
        }
        const float inv = 1.0f / sum;
#pragma unroll
        for (int jx = 0; jx < NJ; ++jx)
            c[((size_t)jx * NI + i0 + i) * NB + b0 + b] = v[jx] * inv;
    }
}

// ---------------------------------------------------------------------------
// wsum_k: partial[kc][j][t*16+q] = split-K partials of
// s[b,j,e] = sum_i c[j,i,b] * u_hat[b,j,i,e].
// R0: B-frags built from fp32 W via pk2bf AND stored to Wb (wv==0) for later
// rounds; c uniform 1/32. Else: B-frags from Wb, c from global.
// grid (j=32, kc=64), block 128 = 2 waves; wave = 2 M-tiles.
// ---------------------------------------------------------------------------
template <bool R0>
__global__ __launch_bounds__(128) void wsum_k(
    const float* __restrict__ x,      // [NB][NI][ND] fp32
    const float* __restrict__ W,      // [NJ][NI][NE][ND] fp32 (R0 only)
    short* __restrict__ Wb,           // [NJ][NIP][NE][32] bf16 (R0: write; else read)
    const float* __restrict__ c,      // [NJ][NI][NB] (unused if R0)
    float* __restrict__ partial)      // [NKC][NJ][128*16]
{
    const int j    = blockIdx.x;
    const int kc   = blockIdx.y;
    const int ip0  = kc * 16;          // 16 i-pairs = 32 i's
    const int t    = threadIdx.x;
    const int wv   = t >> 6;
    const int ln   = t & 63;
    const int m    = ln & 15;
    const int quad = ln >> 4;
    const int isel = quad >> 1;        // which of the 2 i's in the K-chunk
    const int d0   = (quad & 1) * 8;   // which 8 d's

    f32x4 acc[2][2];
#pragma unroll
    for (int a = 0; a < 2; ++a)
#pragma unroll
        for (int n = 0; n < 2; ++n) acc[a][n] = (f32x4){0.f, 0.f, 0.f, 0.f};

#pragma unroll 2
    for (int it = 0; it < 16; ++it) {
        const int ip = ip0 + it;
        const int ia = ip * 2 + isel;
        bfrag bv0, bv1;
        if (R0) {
            // build B-frags from fp32 W: e=m and e=16+m rows, d0..d0+7
            const float4* wp0 = reinterpret_cast<const float4*>(
                W + (((size_t)j * NI + ia) * NE + m) * ND + d0);
            const float4* wp1 = reinterpret_cast<const float4*>(
                W + (((size_t)j * NI + ia) * NE + 16 + m) * ND + d0);
            float4 a0 = wp0[0], a1 = wp0[1], b0f = wp1[0], b1f = wp1[1];
            unsigned* u0 = reinterpret_cast<unsigned*>(&bv0);
            unsigned* u1 = reinterpret_cast<unsigned*>(&bv1);
            u0[0] = pk2bf(a0.x, a0.y); u0[1] = pk2bf(a0.z, a0.w);
            u0[2] = pk2bf(a1.x, a1.y); u0[3] = pk2bf(a1.z, a1.w);
            u1[0] = pk2bf(b0f.x, b0f.y); u1[1] = pk2bf(b0f.z, b0f.w);
            u1[2] = pk2bf(b1f.x, b1f.y); u1[3] = pk2bf(b1f.z, b1f.w);
            if (wv == 0) {   // emit Wb for later rounds (one writer per frag)
                short* dst = Wb + (((size_t)j * NIP + ip) * NE + m) * 32 + quad * 8;
                *reinterpret_cast<bfrag*>(dst) = bv0;
                *reinterpret_cast<bfrag*>(dst + 16 * 32) = bv1;
            }
        } else {
            const short* wp = Wb + (((size_t)j * NIP + ip) * NE + m) * 32 + quad * 8;
            bv0 = *reinterpret_cast<const bfrag*>(wp);
            bv1 = *reinterpret_cast<const bfrag*>(wp + 16 * 32);
        }
#pragma unroll
        for (int mt = 0; mt < 2; ++mt) {
            const int b = (wv * 2 + mt) * 16 + m;
            const float cc = R0 ? (1.0f / NJ)
                                : c[((size_t)j * NI + ia) * NB + b];
            const float4* xp = reinterpret_cast<const float4*>(
                x + ((size_t)b * NI + ia) * ND + d0);
            float4 x0 = xp[0], x1 = xp[1];
            bfrag av;
            unsigned* avu = reinterpret_cast<unsigned*>(&av);
            avu[0] = pk2bf(x0.x * cc, x0.y * cc);
            avu[1] = pk2bf(x0.z * cc, x0.w * cc);
            avu[2] = pk2bf(x1.x * cc, x1.y * cc);
            avu[3] = pk2bf(x1.z * cc, x1.w * cc);
            acc[mt][0] = __builtin_amdgcn_mfma_f32_16x16x32_bf16(av, bv0, acc[mt][0], 0, 0, 0);
            acc[mt][1] = __builtin_amdgcn_mfma_f32_16x16x32_bf16(av, bv1, acc[mt][1], 0, 0, 0);
        }
    }

    // coalesced partial store: thread t owns 16 consecutive floats,
    // q = mt*8 + nt*4 + r.
    float* pbase = partial + ((size_t)kc * NJ + j) * (128 * 16) + t * 16;
#pragma unroll
    for (int mt = 0; mt < 2; ++mt)
#pragma unroll
        for (int nt = 0; nt < 2; ++nt)
            *reinterpret_cast<f32x4*>(pbase + mt * 8 + nt * 4) = acc[mt][nt];
}

// ---------------------------------------------------------------------------
// rs_k: fused reduce (sum over kc) + squash + state update.
// Thread g -> one (b,j,e) via the wsum lane mapping; within a 256-thread
// block, (j,wv,quad) are fixed and the 32 e's of each (b,j) are present ->
// LDS row-norm. mode 0: Oacc = squash(s) (round 0, overwrite);
// mode 1: Oacc += squash(s); mode 2: out = squash(s).
// ---------------------------------------------------------------------------
__global__ __launch_bounds__(256) void rs_k(
    const float* __restrict__ partial,   // [NKC][NJ][2048]
    float* __restrict__ Oacc,            // [NB][NJ][NE]
    float* __restrict__ out,             // [NB][NJ][NE]
    int mode)
{
    const int g    = blockIdx.x * 256 + threadIdx.x;   // 0..65535
    const int j    = g >> 11;
    const int rem  = g & 2047;
    const int tt   = rem >> 4;
    const int q    = rem & 15;
    const int wv   = tt >> 6;
    const int lnn  = tt & 63;
    const int m    = lnn & 15;
    const int quad = lnn >> 4;
    const int mt   = q >> 3;
    const int nt   = (q >> 2) & 1;
    const int r    = q & 3;
    const int b    = (wv * 2 + mt) * 16 + quad * 4 + r;
    const int e    = nt * 16 + m;

    float sum = 0.f;
#pragma unroll 8
    for (int kc = 0; kc < NKC; ++kc)
        sum += partial[(size_t)kc * (NJ * 2048) + g];

    // LDS norm: within block, (mt,r) keys 8 rows x 32 e's.
    __shared__ float lds[256];
    const int li = mt * 128 + r * 32 + e;
    lds[li] = sum;
    __syncthreads();
    const float* row = &lds[mt * 128 + r * 32];
    float p = 0.f;
#pragma unroll
    for (int ee = 0; ee < 32; ++ee) p = fmaf(row[ee], row[ee], p);

    const float scale = p / ((1.0f + p) * sqrtf(p + 1e-7f));
    const float o = scale * sum;
    const size_t off = ((size_t)b * NJ + j) * NE + e;
    if (mode == 2)      out[off]  = o;
    else if (mode == 1) Oacc[off] += o;
    else                Oacc[off] = o;
}

extern "C" void kernel_launch(void* const* d_in, const int* in_sizes, int n_in,
                              void* d_out, int out_size, void* d_ws, size_t ws_size,
                              hipStream_t stream)
{
    (void)in_sizes; (void)n_in; (void)out_size; (void)ws_size;
    const float* x = (const float*)d_in[0];   // [64][2048][16]
    const float* W = (const float*)d_in[1];   // [32][2048][32][16]
    float* out = (float*)d_out;               // [64][32][32]

    // ws layout (~96.3 MB of 512 MB). No memsets needed: every buffer is
    // fully written before first read each launch.
    float* Oacc = (float*)d_ws;                        // 64K floats  (256 KB)
    float* c    = Oacc + NB * NJ * NE;                 // [NJ][NI][NB] (16 MB)
    float* part = c + (size_t)NJ * NI * NB;            // [64][32][2048] (16 MB)
    short* Wb   = (short*)(part + (size_t)NKC * NJ * 2048);  // 32M bf16 (64 MB)

    dim3 gW(NJ, NKC);          // wsum grid
    dim3 gL(NB / 16, NI / 16); // lgsm grid (4, 128)

    // round 0: uniform c = 1/32; also materializes Wb from W.
    wsum_k<true><<<gW, 128, 0, stream>>>(x, W, Wb, c, part);
    rs_k<<<65536 / 256, 256, 0, stream>>>(part, Oacc, out, 0);

    // round 1
    lgsm_k<<<gL, 512, 0, stream>>>(x, Wb, Oacc, c);
    wsum_k<false><<<gW, 128, 0, stream>>>(x, W, Wb, c, part);
    rs_k<<<65536 / 256, 256, 0, stream>>>(part, Oacc, out, 1);

    // round 2
    lgsm_k<<<gL, 512, 0, stream>>>(x, Wb, Oacc, c);
    wsum_k<false><<<gW, 128, 0, stream>>>(x, W, Wb, c, part);
    rs_k<<<65536 / 256, 256, 0, stream>>>(part, Oacc, out, 2);
}

// Round 7
// 440.518 us; speedup vs baseline: 1.1255x; 1.1255x over previous
//
#include <hip/hip_runtime.h>
#include <hip/hip_bf16.h>

#define NB 64     // batch
#define NI 2048   // input capsules
#define ND 16     // d_in
#define NJ 32     // output capsules
#define NE 32     // d_out
#define NIP (NI/2)  // i-pairs
#define NKC 64    // wsum grid kc dimension
#define NSL (NKC*2) // partial slices (2 waves per wsum block)

typedef __attribute__((ext_vector_type(8))) short bfrag;   // 8 bf16 (4 VGPRs)
typedef __attribute__((ext_vector_type(4))) float f32x4;

// float -> bf16 bits, round-to-nearest-even (scalar path)
__device__ inline short f2bf(float f) {
    unsigned u = __float_as_uint(f);
    unsigned r = u + 0x7fffu + ((u >> 16) & 1u);
    return (short)(r >> 16);
}

// two floats -> packed bf16x2 (v_cvt_pk_bf16_f32 on gfx950), RNE
__device__ inline unsigned pk2bf(float a, float b) {
    __hip_bfloat162 h = __float22bfloat162_rn(make_float2(a, b));
    return *reinterpret_cast<unsigned*>(&h);
}

// add value rotated by N within each 16-lane DPP row (row_ror:N)
template <int N>
__device__ inline float rot16_add(float v) {
    int r = __builtin_amdgcn_mov_dpp(__float_as_int(v), 0x120 + N, 0xf, 0xf, false);
    return v + __int_as_float(r);
}

// unpack a dword of 2 bf16, scale by cc, repack (RNE)
__device__ inline unsigned scale_pair(unsigned u, float cc) {
    float f0 = __uint_as_float(u << 16);
    float f1 = __uint_as_float(u & 0xffff0000u);
    return pk2bf(f0 * cc, f1 * cc);
}

// ---------------------------------------------------------------------------
// convw_k: W fp32 [NJ][NI][NE][ND] -> Wb bf16 [NJ][NIP][NE][32]
// (MFMA B-fragment layout; k = isel*16 + d). Full-BW proven kernel.
// ---------------------------------------------------------------------------
__global__ __launch_bounds__(256) void convw_k(const float* __restrict__ W,
                                               short* __restrict__ Wb)
{
    const int t = blockIdx.x * 256 + threadIdx.x;   // 2^21 threads
    const int isel = t & 1;
    const int e    = (t >> 1) & 31;
    const int ip   = (t >> 6) & 1023;
    const int j    = t >> 16;

    const float4* src = reinterpret_cast<const float4*>(
        W + (((size_t)j * NI + ip * 2 + isel) * NE + e) * ND);
    float4 a = src[0], b = src[1], c = src[2], d = src[3];

    bfrag lo, hi;
    lo[0] = f2bf(a.x); lo[1] = f2bf(a.y); lo[2] = f2bf(a.z); lo[3] = f2bf(a.w);
    lo[4] = f2bf(b.x); lo[5] = f2bf(b.y); lo[6] = f2bf(b.z); lo[7] = f2bf(b.w);
    hi[0] = f2bf(c.x); hi[1] = f2bf(c.y); hi[2] = f2bf(c.z); hi[3] = f2bf(c.w);
    hi[4] = f2bf(d.x); hi[5] = f2bf(d.y); hi[6] = f2bf(d.z); hi[7] = f2bf(d.w);

    short* dst = Wb + ((((size_t)j * NIP + ip) * NE + e) * 32) + isel * 16;
    *reinterpret_cast<bfrag*>(dst)     = lo;
    *reinterpret_cast<bfrag*>(dst + 8) = hi;
}

// ---------------------------------------------------------------------------
// convxT_k: x fp32 [NB][NI][ND] -> xT bf16 [NI][NB][ND].
// b fastest across lanes -> coalesced writes; reads touch each line once.
// ---------------------------------------------------------------------------
__global__ __launch_bounds__(256) void convxT_k(const float* __restrict__ x,
                                                short* __restrict__ xT)
{
    const int T = blockIdx.x * 256 + threadIdx.x;   // NI*NB = 131072
    const int i = T >> 6, b = T & 63;
    const float4* src = reinterpret_cast<const float4*>(
        x + ((size_t)b * NI + i) * ND);
    float4 a0 = src[0], a1 = src[1], a2 = src[2], a3 = src[3];
    bfrag lo, hi;
    unsigned* lu = reinterpret_cast<unsigned*>(&lo);
    unsigned* hu = reinterpret_cast<unsigned*>(&hi);
    lu[0] = pk2bf(a0.x, a0.y); lu[1] = pk2bf(a0.z, a0.w);
    lu[2] = pk2bf(a1.x, a1.y); lu[3] = pk2bf(a1.z, a1.w);
    hu[0] = pk2bf(a2.x, a2.y); hu[1] = pk2bf(a2.z, a2.w);
    hu[2] = pk2bf(a3.x, a3.y); hu[3] = pk2bf(a3.z, a3.w);
    short* dst = xT + ((size_t)i * NB + b) * ND;
    *reinterpret_cast<bfrag*>(dst)     = lo;
    *reinterpret_cast<bfrag*>(dst + 8) = hi;
}

// ---------------------------------------------------------------------------
// lgsm_k: fused logits + softmax. Block = 16 b x 16 i x ALL 32 j (8 waves,
// 4 j each). Logits via K=16-padded mfma + DPP e-reduction into 32KB LDS,
// one barrier, softmax over j, write c[j][i][b]. A-frags: single 16B loads
// from xT (wave-contiguous). grid (4 bb, 128 ic).
// ---------------------------------------------------------------------------
__global__ __launch_bounds__(512) void lgsm_k(
    const short* __restrict__ xT,     // [NI][NB][ND] bf16
    const short* __restrict__ Wb,     // [NJ][NIP][NE][32] bf16
    const float* __restrict__ Oacc,   // [NB][NJ][NE]
    float* __restrict__ c)            // [NJ][NI][NB]
{
    const int b0   = blockIdx.x * 16;
    const int i0   = blockIdx.y * 16;
    const int t    = threadIdx.x;
    const int wv   = t >> 6;           // 0..7 -> j-set wv*4..wv*4+3
    const int ln   = t & 63;
    const int m    = ln & 15;
    const int quad = ln >> 4;

    __shared__ float lp[NJ][16][16];   // [j][i][b] 32 KB

    // Hoist Oacc fragments for this wave's 4 j's.
    float O0[4][4], O1[4][4];
#pragma unroll
    for (int jj = 0; jj < 4; ++jj) {
        const int j = wv * 4 + jj;
#pragma unroll
        for (int r = 0; r < 4; ++r) {
            const int b = b0 + quad * 4 + r;
            O0[jj][r] = Oacc[((size_t)b * NJ + j) * NE + m];
            O1[jj][r] = Oacc[((size_t)b * NJ + j) * NE + 16 + m];
        }
    }

    const int  bA  = b0 + m;        // A-operand row (b) this lane supplies
    const bool act = quad < 2;      // quads 0,1 carry k=0..15 (d); 2,3 zero pad
    const int  d0  = quad * 8;

    for (int il = 0; il < 16; ++il) {
        const int i = i0 + il;
        const int ip = i >> 1, isel = i & 1;
        bfrag av = (bfrag)0;
        if (act) {
            av = *reinterpret_cast<const bfrag*>(
                xT + ((size_t)i * NB + bA) * ND + d0);
        }
#pragma unroll
        for (int jj = 0; jj < 4; ++jj) {
            const int j = wv * 4 + jj;
            bfrag bv0 = (bfrag)0, bv1 = (bfrag)0;
            if (act) {
                const short* wp = Wb + (((size_t)j * NIP + ip) * NE + m) * 32
                                     + isel * 16 + d0;
                bv0 = *reinterpret_cast<const bfrag*>(wp);
                bv1 = *reinterpret_cast<const bfrag*>(wp + 16 * 32);
            }
            f32x4 z = {0.f, 0.f, 0.f, 0.f};
            f32x4 U0 = __builtin_amdgcn_mfma_f32_16x16x32_bf16(av, bv0, z, 0, 0, 0);
            f32x4 U1 = __builtin_amdgcn_mfma_f32_16x16x32_bf16(av, bv1, z, 0, 0, 0);

            float v4[4];
#pragma unroll
            for (int r = 0; r < 4; ++r) {
                float v = fmaf(U0[r], O0[jj][r], U1[r] * O1[jj][r]);
                v = rot16_add<1>(v);
                v = rot16_add<2>(v);
                v = rot16_add<4>(v);
                v = rot16_add<8>(v);
                v4[r] = v;
            }
            if (m == 0) {
                *reinterpret_cast<float4*>(&lp[j][il][quad * 4]) =
                    make_float4(v4[0], v4[1], v4[2], v4[3]);
            }
        }
    }
    __syncthreads();

    // softmax over j: threads 0..255 each own one (i,b) row.
    if (t < 256) {
        const int i = t >> 4, b = t & 15;
        float v[NJ];
        float mx = -1e30f;
#pragma unroll
        for (int jx = 0; jx < NJ; ++jx) {
            v[jx] = lp[jx][i][b];
            mx = fmaxf(mx, v[jx]);
        }
        float sum = 0.f;
#pragma unroll
        for (int jx = 0; jx < NJ; ++jx) {
            v[jx] = __expf(v[jx] - mx);
            sum += v[jx];
        }
        const float inv = 1.0f / sum;
#pragma unroll
        for (int jx = 0; jx < NJ; ++jx)
            c[((size_t)jx * NI + i0 + i) * NB + b0 + b] = v[jx] * inv;
    }
}

// ---------------------------------------------------------------------------
// wsum_k: split-K partials of s[b,j,e] = sum_i c[j,i,b] * u_hat[b,j,i,e].
// Wave owns all 4 M-tiles (64 b) -> B-frags amortized x4. A-frag: one 16B
// bf16 load from xT + unpack-scale-repack. Each of the 2 waves handles 8
// K-chunks and writes its own coalesced 2048-float partial slice.
// grid (j=32, kc=64), block 128.
// ---------------------------------------------------------------------------
template <bool R0>
__global__ __launch_bounds__(128, 4) void wsum_k(
    const short* __restrict__ xT,     // [NI][NB][ND] bf16
    const short* __restrict__ Wb,     // [NJ][NIP][NE][32] bf16
    const float* __restrict__ c,      // [NJ][NI][NB] (unused if R0)
    float* __restrict__ partial)      // [NSL][NJ][2048]
{
    const int j    = blockIdx.x;
    const int kc   = blockIdx.y;
    const int t    = threadIdx.x;
    const int wv   = t >> 6;
    const int ln   = t & 63;
    const int m    = ln & 15;
    const int quad = ln >> 4;
    const int isel = quad >> 1;        // which of the 2 i's in the K-chunk
    const int d0   = (quad & 1) * 8;   // which 8 d's (element offset)
    const int ip0  = kc * 16 + wv * 8; // this wave's 8 i-pairs

    f32x4 acc[4][2];
#pragma unroll
    for (int a = 0; a < 4; ++a)
#pragma unroll
        for (int n = 0; n < 2; ++n) acc[a][n] = (f32x4){0.f, 0.f, 0.f, 0.f};

#pragma unroll 2
    for (int it = 0; it < 8; ++it) {
        const int ip = ip0 + it;
        const int ia = ip * 2 + isel;
        const short* wp = Wb + (((size_t)j * NIP + ip) * NE + m) * 32 + quad * 8;
        bfrag bv0 = *reinterpret_cast<const bfrag*>(wp);
        bfrag bv1 = *reinterpret_cast<const bfrag*>(wp + 16 * 32);
#pragma unroll
        for (int mt = 0; mt < 4; ++mt) {
            const int b = mt * 16 + m;
            const float cc = R0 ? (1.0f / NJ)
                                : c[((size_t)j * NI + ia) * NB + b];
            const uint4 xr = *reinterpret_cast<const uint4*>(
                xT + ((size_t)ia * NB + b) * ND + d0);
            bfrag av;
            unsigned* avu = reinterpret_cast<unsigned*>(&av);
            avu[0] = scale_pair(xr.x, cc);
            avu[1] = scale_pair(xr.y, cc);
            avu[2] = scale_pair(xr.z, cc);
            avu[3] = scale_pair(xr.w, cc);
            acc[mt][0] = __builtin_amdgcn_mfma_f32_16x16x32_bf16(av, bv0, acc[mt][0], 0, 0, 0);
            acc[mt][1] = __builtin_amdgcn_mfma_f32_16x16x32_bf16(av, bv1, acc[mt][1], 0, 0, 0);
        }
    }

    // coalesced slice store: group (mt,nt) -> 1KB contiguous per instruction
    const int slice = kc * 2 + wv;
    float* pbase = partial + ((size_t)slice * NJ + j) * 2048;
#pragma unroll
    for (int mt = 0; mt < 4; ++mt)
#pragma unroll
        for (int nt = 0; nt < 2; ++nt)
            *reinterpret_cast<f32x4*>(pbase + (mt * 2 + nt) * 256 + ln * 4)
                = acc[mt][nt];
}

// ---------------------------------------------------------------------------
// rs_k: fused reduce (sum over NSL slices) + squash + state update.
// Block = 512 threads = one (j, mt) pair = 16 b x 32 e -> LDS row-norm.
// mode 0: Oacc = squash(s); mode 1: Oacc += squash(s); mode 2: out = squash(s).
// ---------------------------------------------------------------------------
__global__ __launch_bounds__(512) void rs_k(
    const float* __restrict__ partial,   // [NSL][NJ][2048]
    float* __restrict__ Oacc,            // [NB][NJ][NE]
    float* __restrict__ out,             // [NB][NJ][NE]
    int mode)
{
    const int G    = blockIdx.x * 512 + threadIdx.x;   // 0..65535
    const int j    = G >> 11;
    const int g    = G & 2047;
    const int group = g >> 8;           // 0..7 = mt*2+nt
    const int mt   = group >> 1;
    const int nt   = group & 1;
    const int lnn  = (g >> 2) & 63;
    const int m    = lnn & 15;
    const int quad = lnn >> 4;
    const int r    = g & 3;
    const int b    = mt * 16 + quad * 4 + r;
    const int e    = nt * 16 + m;

    float sum = 0.f;
#pragma unroll 8
    for (int sl = 0; sl < NSL; ++sl)
        sum += partial[((size_t)sl * NJ + j) * 2048 + g];

    // LDS norm: 16 b-rows x 32 e per block (mt fixed within block).
    __shared__ float lds[512];
    const int row = quad * 4 + r;        // 0..15
    lds[row * 32 + e] = sum;
    __syncthreads();
    const float* rp = &lds[row * 32];
    float p = 0.f;
#pragma unroll
    for (int ee = 0; ee < 32; ++ee) p = fmaf(rp[ee], rp[ee], p);

    const float scale = p / ((1.0f + p) * sqrtf(p + 1e-7f));
    const float o = scale * sum;
    const size_t off = ((size_t)b * NJ + j) * NE + e;
    if (mode == 2)      out[off]  = o;
    else if (mode == 1) Oacc[off] += o;
    else                Oacc[off] = o;
}

extern "C" void kernel_launch(void* const* d_in, const int* in_sizes, int n_in,
                              void* d_out, int out_size, void* d_ws, size_t ws_size,
                              hipStream_t stream)
{
    (void)in_sizes; (void)n_in; (void)out_size; (void)ws_size;
    const float* x = (const float*)d_in[0];   // [64][2048][16]
    const float* W = (const float*)d_in[1];   // [32][2048][32][16]
    float* out = (float*)d_out;               // [64][32][32]

    // ws layout (~120 MB of 512 MB). Every buffer fully written before read.
    float* Oacc = (float*)d_ws;                        // 64K floats  (256 KB)
    float* c    = Oacc + NB * NJ * NE;                 // [NJ][NI][NB] (16 MB)
    float* part = c + (size_t)NJ * NI * NB;            // [NSL][NJ][2048] (32 MB)
    short* Wb   = (short*)(part + (size_t)NSL * NJ * 2048);  // 32M bf16 (64 MB)
    short* xT   = Wb + (size_t)NJ * NIP * NE * 32;           // 4M bf16  (8 MB)

    // pre-convert: W -> Wb (fragment layout), x -> xT (transposed bf16)
    convw_k<<<(NJ * NIP * NE * 2) / 256, 256, 0, stream>>>(W, Wb);
    convxT_k<<<(NI * NB) / 256, 256, 0, stream>>>(x, xT);

    dim3 gW(NJ, NKC);          // wsum grid
    dim3 gL(NB / 16, NI / 16); // lgsm grid (4, 128)

    // round 0: uniform c = 1/32
    wsum_k<true><<<gW, 128, 0, stream>>>(xT, Wb, c, part);
    rs_k<<<65536 / 512, 512, 0, stream>>>(part, Oacc, out, 0);

    // round 1
    lgsm_k<<<gL, 512, 0, stream>>>(xT, Wb, Oacc, c);
    wsum_k<false><<<gW, 128, 0, stream>>>(xT, Wb, c, part);
    rs_k<<<65536 / 512, 512, 0, stream>>>(part, Oacc, out, 1);

    // round 2
    lgsm_k<<<gL, 512, 0, stream>>>(xT, Wb, Oacc, c);
    wsum_k<false><<<gW, 128, 0, stream>>>(xT, Wb, c, part);
    rs_k<<<65536 / 512, 512, 0, stream>>>(part, Oacc, out, 2);
}